// Round 12
// baseline (147.745 us; speedup 1.0000x reference)
//
#include <hip/hip_runtime.h>

#define LN_EPS 1e-5f

__device__ __forceinline__ float dot8(float4 a0, float4 a1, float4 b0, float4 b1) {
    return a0.x * b0.x + a0.y * b0.y + a0.z * b0.z + a0.w * b0.w +
           a1.x * b1.x + a1.y * b1.y + a1.z * b1.z + a1.w * b1.w;
}

// ---------------------------------------------------------------------------
// Kernel 1 (v2): embed + row attention + residual + LN -> msaR.
// 512 blocks (b,s,query-half) x 1024 threads, __launch_bounds__(1024,8):
// 2 blocks/CU x 16 waves = 32 waves/CU (100% of wave cap, was 16) and all
// per-thread serial chains halved vs R11: QKV 12->6 dots, attention 16->8
// keys, proj 2->1 output (fused with LN; 3 barriers -> 2). Halved live state
// (sc[8]+a[8]) keeps VGPR under the 64 cap that R6's fuller kernel already
// met -- avoiding the R7 spill trap.
// ---------------------------------------------------------------------------
__global__ __launch_bounds__(1024, 8) void k_row(
    const float* __restrict__ ctcf, const float* __restrict__ hac,
    const float* __restrict__ me1,  const float* __restrict__ me3,
    const float* __restrict__ ew,   const float* __restrict__ eb,
    const float* __restrict__ pe,
    const float* __restrict__ w_in, const float* __restrict__ b_in,
    const float* __restrict__ w_out,const float* __restrict__ b_out,
    const float* __restrict__ ln_g, const float* __restrict__ ln_b,
    float* __restrict__ msaR)
{
    __shared__ float sqkv[64 * 100];    // 25.6 KB
    __shared__ float so[32][36];        // 4.6 KB -> 30.2 KB total

    const int blk = blockIdx.x;
    const int qh  = blk & 1;
    const int s   = (blk >> 1) & 3;
    const int b   = blk >> 3;
    const int qbase = qh * 32;
    const int tid = threadIdx.x;

    const float* chip = (s == 0) ? ctcf : (s == 1) ? hac : (s == 2) ? me1 : me3;

    // ---- QKV: thread (l = tid&63, cgi = tid>>6 in 0..15), 6 cols each ----
    {
        const int l   = tid & 63;
        const int cgi = __builtin_amdgcn_readfirstlane(tid >> 6);  // uniform

        float xr[32];
        {
            const float cv = chip[b * 64 + l];
            const float4* pe4 = (const float4*)&pe[l * 32];
            const float4* ew4 = (const float4*)ew;
            const float4* eb4 = (const float4*)eb;
#pragma unroll
            for (int c4 = 0; c4 < 8; ++c4) {
                float4 pv = pe4[c4], e = ew4[c4], bb = eb4[c4];
                xr[c4 * 4 + 0] = cv * e.x + bb.x + pv.x;
                xr[c4 * 4 + 1] = cv * e.y + bb.y + pv.y;
                xr[c4 * 4 + 2] = cv * e.z + bb.z + pv.z;
                xr[c4 * 4 + 3] = cv * e.w + bb.w + pv.w;
            }
        }
#pragma unroll
        for (int i = 0; i < 6; ++i) {
            const int cc = i * 16 + cgi;          // 0..95, wave-uniform
            const float4* wr4 = (const float4*)&w_in[cc * 32];
            float acc = b_in[cc];
#pragma unroll
            for (int c4 = 0; c4 < 8; ++c4) {
                float4 wv = wr4[c4];
                acc += xr[c4 * 4 + 0] * wv.x + xr[c4 * 4 + 1] * wv.y +
                       xr[c4 * 4 + 2] * wv.z + xr[c4 * 4 + 3] * wv.w;
            }
            sqkv[l * 100 + cc] = acc;
        }
    }
    __syncthreads();

    // ---- attention: h = tid>>8 (0..3), q = (tid>>3)&31, kc = tid&7 ----
    {
        const int h  = tid >> 8;
        const int q  = (tid >> 3) & 31;
        const int kc = tid & 7;
        const int lq = qbase + q;
        const float4* qp = (const float4*)&sqkv[lq * 100 + h * 8];
        float4 q0 = qp[0], q1 = qp[1];
        const float scale = 0.35355339059327373f;  // 1/sqrt(8)

        // pass 1: 8 scores (bank-staggered key order)
        float sc[8];
#pragma unroll
        for (int jj = 0; jj < 8; ++jj) {
            const int j = kc * 8 + ((jj + kc) & 7);
            const float4* kp = (const float4*)&sqkv[j * 100 + 32 + h * 8];
            sc[jj] = dot8(q0, q1, kp[0], kp[1]) * scale;
        }
        float mx = fmaxf(fmaxf(fmaxf(sc[0], sc[1]), fmaxf(sc[2], sc[3])),
                         fmaxf(fmaxf(sc[4], sc[5]), fmaxf(sc[6], sc[7])));
        mx = fmaxf(mx, __shfl_xor(mx, 1, 64));
        mx = fmaxf(mx, __shfl_xor(mx, 2, 64));
        mx = fmaxf(mx, __shfl_xor(mx, 4, 64));

        // pass 2: independent exps + weighted V
        float den = 0.f, a[8];
#pragma unroll
        for (int dd = 0; dd < 8; ++dd) a[dd] = 0.f;
#pragma unroll
        for (int jj = 0; jj < 8; ++jj) {
            const int j = kc * 8 + ((jj + kc) & 7);
            float w = __expf(sc[jj] - mx);
            den += w;
            const float4* vp = (const float4*)&sqkv[j * 100 + 64 + h * 8];
            float4 v0 = vp[0], v1 = vp[1];
            a[0] += w * v0.x;  a[1] += w * v0.y;
            a[2] += w * v0.z;  a[3] += w * v0.w;
            a[4] += w * v1.x;  a[5] += w * v1.y;
            a[6] += w * v1.z;  a[7] += w * v1.w;
        }
#pragma unroll
        for (int off = 1; off <= 4; off <<= 1) {
            den += __shfl_xor(den, off, 64);
#pragma unroll
            for (int dd = 0; dd < 8; ++dd) a[dd] += __shfl_xor(a[dd], off, 64);
        }
        float inv = 1.f / den;
        // lane kc writes dim kc (static selection chain)
        float rv = a[0];
        if      (kc == 1) rv = a[1];
        else if (kc == 2) rv = a[2];
        else if (kc == 3) rv = a[3];
        else if (kc == 4) rv = a[4];
        else if (kc == 5) rv = a[5];
        else if (kc == 6) rv = a[6];
        else if (kc == 7) rv = a[7];
        so[q][h * 8 + kc] = rv * inv;
    }
    __syncthreads();

    // ---- fused out-proj + residual (recomputed) + LN + write ----
    // thread (r = tid>>5 in 0..31, c = tid&31): 1 output/thread; LN over the
    // 32 c-lanes via in-wave shuffles (offsets <=16 stay in the 32-lane half).
    {
        const int r  = tid >> 5;
        const int c  = tid & 31;
        const int lg = qbase + r;
        const float cvr = chip[b * 64 + lg];

        float orow[32];
        const float4* sop = (const float4*)&so[r][0];
#pragma unroll
        for (int k4 = 0; k4 < 8; ++k4) {
            float4 t = sop[k4];
            orow[k4 * 4 + 0] = t.x;  orow[k4 * 4 + 1] = t.y;
            orow[k4 * 4 + 2] = t.z;  orow[k4 * 4 + 3] = t.w;
        }
        const float4* wr4 = (const float4*)&w_out[c * 32];
        float acc = b_out[c] + (cvr * ew[c] + eb[c] + pe[lg * 32 + c]);
#pragma unroll
        for (int k4 = 0; k4 < 8; ++k4) {
            float4 wv = wr4[k4];
            acc += orow[k4 * 4 + 0] * wv.x + orow[k4 * 4 + 1] * wv.y +
                   orow[k4 * 4 + 2] * wv.z + orow[k4 * 4 + 3] * wv.w;
        }
        float s1 = acc;
#pragma unroll
        for (int off = 16; off >= 1; off >>= 1) s1 += __shfl_xor(s1, off, 64);
        float mu = s1 * (1.f / 32.f);
        float d = acc - mu;
        float s2 = d * d;
#pragma unroll
        for (int off = 16; off >= 1; off >>= 1) s2 += __shfl_xor(s2, off, 64);
        float rstd = rsqrtf(s2 * (1.f / 32.f) + LN_EPS);
        msaR[((b * 4 + s) * 64 + lg) * 32 + c] = d * rstd * ln_g[c] + ln_b[c];
    }
}

// ---------------------------------------------------------------------------
// Kernel 2: column attention (unchanged from R11, part of the 143.6 best).
// 1024 blocks (b, 4-bin chunk) x 256 threads, (256,4).
// ---------------------------------------------------------------------------
__global__ __launch_bounds__(256, 4) void k_col(
    const float* __restrict__ msaR,
    const float* __restrict__ w_in, const float* __restrict__ b_in,
    const float* __restrict__ w_out,const float* __restrict__ b_out,
    const float* __restrict__ ln_g, const float* __restrict__ ln_b,
    float* __restrict__ m_out, float* __restrict__ nrm_out)
{
    __shared__ float sx[16][33];
    __shared__ float sqkv[16 * 100];
    __shared__ float so[16][33];

    const int bx = blockIdx.x;
    const int b  = bx >> 4;
    const int l0 = (bx & 15) * 4;
    const int tid = threadIdx.x;

    for (int n = tid; n < 512; n += 256) {
        int r = n >> 5, c = n & 31;
        int lo = r >> 2, s = r & 3;
        sx[r][c] = msaR[((b * 4 + s) * 64 + l0 + lo) * 32 + c];
    }
    __syncthreads();

    {
        const int rr = tid & 15;
        const int cg = tid >> 4;
        float xr[32];
#pragma unroll
        for (int c = 0; c < 32; ++c) xr[c] = sx[rr][c];
#pragma unroll
        for (int i = 0; i < 6; ++i) {
            int cc = i * 16 + cg;
            const float4* wr4 = (const float4*)&w_in[cc * 32];
            float acc = b_in[cc];
#pragma unroll
            for (int c4 = 0; c4 < 8; ++c4) {
                float4 wv = wr4[c4];
                acc += xr[c4 * 4 + 0] * wv.x + xr[c4 * 4 + 1] * wv.y +
                       xr[c4 * 4 + 2] * wv.z + xr[c4 * 4 + 3] * wv.w;
            }
            sqkv[rr * 100 + cc] = acc;
        }
    }
    __syncthreads();

    if (tid < 64) {
        const int lo = tid >> 4, h = (tid >> 2) & 3, ia = tid & 3;
        const float scale = 0.35355339059327373f;
        const float4* qp = (const float4*)&sqkv[(lo * 4 + ia) * 100 + h * 8];
        float4 q0 = qp[0], q1 = qp[1];
        float sc[4];
        float mx = -1e30f;
#pragma unroll
        for (int jj = 0; jj < 4; ++jj) {
            const float4* kp = (const float4*)&sqkv[(lo * 4 + jj) * 100 + 32 + h * 8];
            sc[jj] = dot8(q0, q1, kp[0], kp[1]) * scale;
            mx = fmaxf(mx, sc[jj]);
        }
        float den = 0.f;
#pragma unroll
        for (int jj = 0; jj < 4; ++jj) { sc[jj] = __expf(sc[jj] - mx); den += sc[jj]; }
        float inv = 1.f / den;
        float a[8];
#pragma unroll
        for (int dd = 0; dd < 8; ++dd) a[dd] = 0.f;
#pragma unroll
        for (int jj = 0; jj < 4; ++jj) {
            const float4* vp = (const float4*)&sqkv[(lo * 4 + jj) * 100 + 64 + h * 8];
            float4 v0 = vp[0], v1 = vp[1];
            float wgt = sc[jj];
            a[0] += wgt * v0.x;  a[1] += wgt * v0.y;
            a[2] += wgt * v0.z;  a[3] += wgt * v0.w;
            a[4] += wgt * v1.x;  a[5] += wgt * v1.y;
            a[6] += wgt * v1.z;  a[7] += wgt * v1.w;
        }
#pragma unroll
        for (int dd = 0; dd < 8; ++dd) so[lo * 4 + ia][h * 8 + dd] = a[dd] * inv;
    }
    __syncthreads();

    {
        const int r2 = tid & 15;
        const int cB = tid >> 4;
        float orow[32];
#pragma unroll
        for (int k = 0; k < 32; ++k) orow[k] = so[r2][k];
#pragma unroll
        for (int i = 0; i < 2; ++i) {
            int c = cB + i * 16;
            const float4* wr4 = (const float4*)&w_out[c * 32];
            float acc = b_out[c] + sx[r2][c];
#pragma unroll
            for (int k4 = 0; k4 < 8; ++k4) {
                float4 wv = wr4[k4];
                acc += orow[k4 * 4 + 0] * wv.x + orow[k4 * 4 + 1] * wv.y +
                       orow[k4 * 4 + 2] * wv.z + orow[k4 * 4 + 3] * wv.w;
            }
            sqkv[r2 * 100 + c] = acc;
        }
    }
    __syncthreads();

    {
        const int c = tid & 31;
#pragma unroll
        for (int p = 0; p < 2; ++p) {
            int r = p * 8 + (tid >> 5);
            float v = sqkv[r * 100 + c];
            float s1 = v;
#pragma unroll
            for (int off = 16; off >= 1; off >>= 1) s1 += __shfl_xor(s1, off, 64);
            float mu = s1 * (1.f / 32.f);
            float d = v - mu;
            float s2 = d * d;
#pragma unroll
            for (int off = 16; off >= 1; off >>= 1) s2 += __shfl_xor(s2, off, 64);
            float rstd = rsqrtf(s2 * (1.f / 32.f) + LN_EPS);
            so[r][c] = d * rstd;
        }
    }
    __syncthreads();

    if (tid < 128) {
        const int lo = tid >> 5, c = tid & 31;
        float mval = 0.25f * (so[lo * 4 + 0][c] + so[lo * 4 + 1][c] +
                              so[lo * 4 + 2][c] + so[lo * 4 + 3][c]) * ln_g[c] + ln_b[c];
        m_out[(b * 64 + l0 + lo) * 32 + c] = mval;
        float q2 = mval * mval;
#pragma unroll
        for (int off = 16; off >= 1; off >>= 1) q2 += __shfl_xor(q2, off, 64);
        if (c == 0) nrm_out[b * 64 + l0 + lo] = sqrtf(q2);
    }
}

// ---------------------------------------------------------------------------
// Kernel 3: pair features (unchanged, 19.6 us measured). 1024 x 256, (256,4).
// ---------------------------------------------------------------------------
__global__ __launch_bounds__(256, 4) void k_pair(
    const float* __restrict__ m, const float* __restrict__ nrm,
    const float* __restrict__ pw, const float* __restrict__ pb,
    const float* __restrict__ pg, const float* __restrict__ pbeta,
    float* __restrict__ out)
{
    __shared__ float smj[64][36];
    __shared__ float sT[4 * 520];
    __shared__ float snj[64];
    __shared__ float sbias[16], sgam[16], sbet[16];

    const int bx = blockIdx.x;
    const int b  = bx >> 4;
    const int i0 = (bx & 15) * 4;
    const int tid = threadIdx.x;
    const int lane = tid & 63, w = tid >> 6;

    const int rem0 = tid, rem1 = tid + 256;
    const float* pw0 = pw + (rem0 >> 5) * 1024 + (rem0 & 31);
    const float* pw1 = pw + (rem1 >> 5) * 1024 + (rem1 & 31);
    float w0[32], w1[32];
#pragma unroll
    for (int c = 0; c < 32; ++c) { w0[c] = pw0[c * 32]; w1[c] = pw1[c * 32]; }

    const float* mb = m + b * 2048;
    for (int n = tid; n < 2048; n += 256) smj[n >> 5][n & 31] = mb[n];
    if (tid < 64) snj[tid] = nrm[b * 64 + tid];
    if (tid < 16) {
        sbias[tid] = pb[tid];
        sgam[tid]  = pg[tid];
        sbet[tid]  = pbeta[tid];
    }
    __syncthreads();

#pragma unroll
    for (int il = 0; il < 4; ++il) {
        const float4* mr4 = (const float4*)&smj[i0 + il][0];
        float a0 = 0.f, a1 = 0.f;
#pragma unroll
        for (int c4 = 0; c4 < 8; ++c4) {
            float4 mv = mr4[c4];
            a0 += mv.x * w0[c4 * 4 + 0] + mv.y * w0[c4 * 4 + 1] +
                  mv.z * w0[c4 * 4 + 2] + mv.w * w0[c4 * 4 + 3];
            a1 += mv.x * w1[c4 * 4 + 0] + mv.y * w1[c4 * 4 + 1] +
                  mv.z * w1[c4 * 4 + 2] + mv.w * w1[c4 * 4 + 3];
        }
        sT[il * 520 + rem0] = a0;
        sT[il * 520 + rem1] = a1;
    }
    __syncthreads();

    const int j = lane;
    float mj[32];
    {
        const float4* mjp = (const float4*)&smj[j][0];
#pragma unroll
        for (int d4 = 0; d4 < 8; ++d4) {
            float4 t = mjp[d4];
            mj[d4 * 4 + 0] = t.x;  mj[d4 * 4 + 1] = t.y;
            mj[d4 * 4 + 2] = t.z;  mj[d4 * 4 + 3] = t.w;
        }
    }
    const float nj = snj[j];

    {
        const int il = w;
        const int ig = i0 + il;
        const float invn = 1.f / fmaxf(snj[ig] * nj, 1e-6f);
        float f[16];
#pragma unroll
        for (int cp = 0; cp < 16; ++cp) {
            const float4* tr = (const float4*)&sT[il * 520 + cp * 32];
            float acc = 0.f;
#pragma unroll
            for (int d4 = 0; d4 < 8; ++d4) {
                float4 tv = tr[d4];
                acc += tv.x * mj[d4 * 4 + 0] + tv.y * mj[d4 * 4 + 1] +
                       tv.z * mj[d4 * 4 + 2] + tv.w * mj[d4 * 4 + 3];
            }
            f[cp] = acc * invn + sbias[cp];
        }
        float mu = 0.f;
#pragma unroll
        for (int cp = 0; cp < 16; ++cp) mu += f[cp];
        mu *= (1.f / 16.f);
        float var = 0.f;
#pragma unroll
        for (int cp = 0; cp < 16; ++cp) { float d = f[cp] - mu; var += d * d; }
        var *= (1.f / 16.f);
        const float rstd = rsqrtf(var + LN_EPS);
#pragma unroll
        for (int cp = 0; cp < 16; ++cp) {
            float v = (f[cp] - mu) * rstd * sgam[cp] + sbet[cp];
            float sl = v / (1.f + __expf(-v));
            out[((b * 16 + cp) * 64 + ig) * 64 + j] = sl;
        }
    }
}

// ---------------------------------------------------------------------------
extern "C" void kernel_launch(void* const* d_in, const int* in_sizes, int n_in,
                              void* d_out, int out_size, void* d_ws, size_t ws_size,
                              hipStream_t stream) {
    const float* ctcf  = (const float*)d_in[0];
    const float* hac   = (const float*)d_in[1];
    const float* me1   = (const float*)d_in[2];
    const float* me3   = (const float*)d_in[3];
    const float* ew    = (const float*)d_in[4];
    const float* ebias = (const float*)d_in[5];
    const float* pe    = (const float*)d_in[6];
    const float* riw   = (const float*)d_in[7];
    const float* rib   = (const float*)d_in[8];
    const float* row_  = (const float*)d_in[9];
    const float* rob   = (const float*)d_in[10];
    const float* rlg   = (const float*)d_in[11];
    const float* rlb   = (const float*)d_in[12];
    const float* ciw   = (const float*)d_in[13];
    const float* cib   = (const float*)d_in[14];
    const float* cow   = (const float*)d_in[15];
    const float* cob   = (const float*)d_in[16];
    const float* clg   = (const float*)d_in[17];
    const float* clb   = (const float*)d_in[18];
    const float* pw    = (const float*)d_in[19];
    const float* pb    = (const float*)d_in[20];
    const float* pg    = (const float*)d_in[21];
    const float* pbt   = (const float*)d_in[22];

    float* outp = (float*)d_out;

    // msaR (2 MB) borrows d_out (16 MB): fully consumed by k_col before
    // k_pair writes out (serial stream). m + norms in ws (~528 KB).
    float* msaR = (float*)d_out;
    float* mbuf = (float*)d_ws;                  // 64*64*32 floats
    float* nbuf = mbuf + 64 * 64 * 32;           // 64*64 floats

    k_row<<<512, 1024, 0, stream>>>(ctcf, hac, me1, me3, ew, ebias, pe,
                                    riw, rib, row_, rob, rlg, rlb, msaR);
    k_col<<<1024, 256, 0, stream>>>(msaR, ciw, cib, cow, cob, clg, clb,
                                    mbuf, nbuf);
    k_pair<<<1024, 256, 0, stream>>>(mbuf, nbuf, pw, pb, pg, pbt, outp);
}

// Round 13
// 144.659 us; speedup vs baseline: 1.0213x; 1.0213x over previous
//
#include <hip/hip_runtime.h>

#define LN_EPS 1e-5f

__device__ __forceinline__ float dot8(float4 a0, float4 a1, float4 b0, float4 b1) {
    return a0.x * b0.x + a0.y * b0.y + a0.z * b0.z + a0.w * b0.w +
           a1.x * b1.x + a1.y * b1.y + a1.z * b1.z + a1.w * b1.w;
}

// ---------------------------------------------------------------------------
// R13 = revert to R11 (proven best, 143.6 us, absmax 0.0078).
// R12's (1024,8) k_row capped VGPR at 64 < ~90 live floats -> spill pressure,
// +4 us. The (512,4)/128-VGPR point below is the verified optimum of the
// occupancy-vs-registers trade for this kernel family.
// ---------------------------------------------------------------------------

// ---------------------------------------------------------------------------
// Kernel 1: embed + row attention (64 bins) + residual + LN -> msaR.
// 512 blocks (b,s,query-half) x 512 threads, (512,4).
// ---------------------------------------------------------------------------
__global__ __launch_bounds__(512, 4) void k_row(
    const float* __restrict__ ctcf, const float* __restrict__ hac,
    const float* __restrict__ me1,  const float* __restrict__ me3,
    const float* __restrict__ ew,   const float* __restrict__ eb,
    const float* __restrict__ pe,
    const float* __restrict__ w_in, const float* __restrict__ b_in,
    const float* __restrict__ w_out,const float* __restrict__ b_out,
    const float* __restrict__ ln_g, const float* __restrict__ ln_b,
    float* __restrict__ msaR)
{
    __shared__ float sqkv[64 * 100];
    __shared__ float so[32][36];

    const int blk = blockIdx.x;
    const int qh  = blk & 1;
    const int s   = (blk >> 1) & 3;
    const int b   = blk >> 3;
    const int qbase = qh * 32;
    const int tid = threadIdx.x;

    const float* chip = (s == 0) ? ctcf : (s == 1) ? hac : (s == 2) ? me1 : me3;

    const int l  = tid & 63;
    const int cg = __builtin_amdgcn_readfirstlane(tid >> 6);

    // fused embed into registers
    float xr[32];
    {
        const float cv = chip[b * 64 + l];
        const float4* pe4 = (const float4*)&pe[l * 32];
        const float4* ew4 = (const float4*)ew;
        const float4* eb4 = (const float4*)eb;
#pragma unroll
        for (int c4 = 0; c4 < 8; ++c4) {
            float4 pv = pe4[c4], e = ew4[c4], bb = eb4[c4];
            xr[c4 * 4 + 0] = cv * e.x + bb.x + pv.x;
            xr[c4 * 4 + 1] = cv * e.y + bb.y + pv.y;
            xr[c4 * 4 + 2] = cv * e.z + bb.z + pv.z;
            xr[c4 * 4 + 3] = cv * e.w + bb.w + pv.w;
        }
    }

    // QKV: contiguous 12-col chunk per wave -> 3 ds_write_b128
    {
        const int cc0 = cg * 12;
        float acc[12];
#pragma unroll
        for (int ii = 0; ii < 12; ++ii) acc[ii] = b_in[cc0 + ii];
#pragma unroll
        for (int ii = 0; ii < 12; ++ii) {
            const float4* wr4 = (const float4*)&w_in[(cc0 + ii) * 32];
#pragma unroll
            for (int c4 = 0; c4 < 8; ++c4) {
                float4 wv = wr4[c4];
                acc[ii] += xr[c4 * 4 + 0] * wv.x + xr[c4 * 4 + 1] * wv.y +
                           xr[c4 * 4 + 2] * wv.z + xr[c4 * 4 + 3] * wv.w;
            }
        }
        float* dst = &sqkv[l * 100 + cc0];
        *(float4*)(dst + 0) = make_float4(acc[0], acc[1], acc[2],  acc[3]);
        *(float4*)(dst + 4) = make_float4(acc[4], acc[5], acc[6],  acc[7]);
        *(float4*)(dst + 8) = make_float4(acc[8], acc[9], acc[10], acc[11]);
    }
    __syncthreads();

    // attention, two-pass: thread (h = tid>>7, q = (tid>>2)&31, kc = tid&3)
    {
        const int h  = tid >> 7;
        const int q  = (tid >> 2) & 31;
        const int kc = tid & 3;
        const int lq = qbase + q;
        const float4* qp = (const float4*)&sqkv[lq * 100 + h * 8];
        float4 q0 = qp[0], q1 = qp[1];
        const float scale = 0.35355339059327373f;  // 1/sqrt(8)

        float sc[16];
#pragma unroll
        for (int jj = 0; jj < 16; ++jj) {
            const int j = kc * 16 + ((jj + kc) & 15);   // bank-staggered
            const float4* kp = (const float4*)&sqkv[j * 100 + 32 + h * 8];
            sc[jj] = dot8(q0, q1, kp[0], kp[1]) * scale;
        }
        float m0 = fmaxf(fmaxf(fmaxf(sc[0], sc[1]),  fmaxf(sc[2], sc[3])),
                         fmaxf(fmaxf(sc[4], sc[5]),  fmaxf(sc[6], sc[7])));
        float m1 = fmaxf(fmaxf(fmaxf(sc[8], sc[9]),  fmaxf(sc[10], sc[11])),
                         fmaxf(fmaxf(sc[12], sc[13]), fmaxf(sc[14], sc[15])));
        float mx = fmaxf(m0, m1);
        mx = fmaxf(mx, __shfl_xor(mx, 1, 64));
        mx = fmaxf(mx, __shfl_xor(mx, 2, 64));

        float den = 0.f, a[8];
#pragma unroll
        for (int dd = 0; dd < 8; ++dd) a[dd] = 0.f;
#pragma unroll
        for (int jj = 0; jj < 16; ++jj) {
            const int j = kc * 16 + ((jj + kc) & 15);
            float w = __expf(sc[jj] - mx);
            den += w;
            const float4* vp = (const float4*)&sqkv[j * 100 + 64 + h * 8];
            float4 v0 = vp[0], v1 = vp[1];
            a[0] += w * v0.x;  a[1] += w * v0.y;
            a[2] += w * v0.z;  a[3] += w * v0.w;
            a[4] += w * v1.x;  a[5] += w * v1.y;
            a[6] += w * v1.z;  a[7] += w * v1.w;
        }
#pragma unroll
        for (int off = 1; off <= 2; off <<= 1) {
            den += __shfl_xor(den, off, 64);
#pragma unroll
            for (int dd = 0; dd < 8; ++dd) a[dd] += __shfl_xor(a[dd], off, 64);
        }
        float inv = 1.f / den;
        float r0, r1;
        if      (kc == 0) { r0 = a[0]; r1 = a[1]; }
        else if (kc == 1) { r0 = a[2]; r1 = a[3]; }
        else if (kc == 2) { r0 = a[4]; r1 = a[5]; }
        else              { r0 = a[6]; r1 = a[7]; }
        so[q][h * 8 + kc * 2 + 0] = r0 * inv;
        so[q][h * 8 + kc * 2 + 1] = r1 * inv;
    }
    __syncthreads();

    // out proj + residual (recomputed) -> sqkv rows 0..31
    {
        const int lq2 = tid & 31;
        const int cB  = tid >> 5;
        const int lg  = qbase + lq2;
        const float cvr = chip[b * 64 + lg];
        float orow[32];
        const float4* sop = (const float4*)&so[lq2][0];
#pragma unroll
        for (int k4 = 0; k4 < 8; ++k4) {
            float4 t = sop[k4];
            orow[k4 * 4 + 0] = t.x;  orow[k4 * 4 + 1] = t.y;
            orow[k4 * 4 + 2] = t.z;  orow[k4 * 4 + 3] = t.w;
        }
#pragma unroll
        for (int i = 0; i < 2; ++i) {
            int c = cB + i * 16;
            const float4* wr4 = (const float4*)&w_out[c * 32];
            float acc = b_out[c] + (cvr * ew[c] + eb[c] + pe[lg * 32 + c]);
#pragma unroll
            for (int k4 = 0; k4 < 8; ++k4) {
                float4 wv = wr4[k4];
                acc += orow[k4 * 4 + 0] * wv.x + orow[k4 * 4 + 1] * wv.y +
                       orow[k4 * 4 + 2] * wv.z + orow[k4 * 4 + 3] * wv.w;
            }
            sqkv[lq2 * 100 + c] = acc;
        }
    }
    __syncthreads();

    // LN + write via 32-lane shuffle reductions
    {
        const int c = tid & 31;
#pragma unroll
        for (int p = 0; p < 2; ++p) {
            int r = p * 16 + (tid >> 5);
            float v = sqkv[r * 100 + c];
            float s1 = v;
#pragma unroll
            for (int off = 16; off >= 1; off >>= 1) s1 += __shfl_xor(s1, off, 64);
            float mu = s1 * (1.f / 32.f);
            float d = v - mu;
            float s2 = d * d;
#pragma unroll
            for (int off = 16; off >= 1; off >>= 1) s2 += __shfl_xor(s2, off, 64);
            float rstd = rsqrtf(s2 * (1.f / 32.f) + LN_EPS);
            msaR[((b * 4 + s) * 64 + qbase + r) * 32 + c] = d * rstd * ln_g[c] + ln_b[c];
        }
    }
}

// ---------------------------------------------------------------------------
// Kernel 2: column attention (4 tracks) + residual + LN + track mean + norm.
// 1024 blocks (b, 4-bin chunk) x 256 threads, (256,4).
// ---------------------------------------------------------------------------
__global__ __launch_bounds__(256, 4) void k_col(
    const float* __restrict__ msaR,
    const float* __restrict__ w_in, const float* __restrict__ b_in,
    const float* __restrict__ w_out,const float* __restrict__ b_out,
    const float* __restrict__ ln_g, const float* __restrict__ ln_b,
    float* __restrict__ m_out, float* __restrict__ nrm_out)
{
    __shared__ float sx[16][33];
    __shared__ float sqkv[16 * 100];
    __shared__ float so[16][33];

    const int bx = blockIdx.x;
    const int b  = bx >> 4;
    const int l0 = (bx & 15) * 4;
    const int tid = threadIdx.x;

    for (int n = tid; n < 512; n += 256) {
        int r = n >> 5, c = n & 31;
        int lo = r >> 2, s = r & 3;
        sx[r][c] = msaR[((b * 4 + s) * 64 + l0 + lo) * 32 + c];
    }
    __syncthreads();

    // qkv: 16 rows x 96 cols, 6 outputs/thread
    {
        const int rr = tid & 15;
        const int cg = tid >> 4;
        float xr[32];
#pragma unroll
        for (int c = 0; c < 32; ++c) xr[c] = sx[rr][c];
#pragma unroll
        for (int i = 0; i < 6; ++i) {
            int cc = i * 16 + cg;
            const float4* wr4 = (const float4*)&w_in[cc * 32];
            float acc = b_in[cc];
#pragma unroll
            for (int c4 = 0; c4 < 8; ++c4) {
                float4 wv = wr4[c4];
                acc += xr[c4 * 4 + 0] * wv.x + xr[c4 * 4 + 1] * wv.y +
                       xr[c4 * 4 + 2] * wv.z + xr[c4 * 4 + 3] * wv.w;
            }
            sqkv[rr * 100 + cc] = acc;
        }
    }
    __syncthreads();

    // attention over 4 tracks: 64 units (lo, h, ia)
    if (tid < 64) {
        const int lo = tid >> 4, h = (tid >> 2) & 3, ia = tid & 3;
        const float scale = 0.35355339059327373f;
        const float4* qp = (const float4*)&sqkv[(lo * 4 + ia) * 100 + h * 8];
        float4 q0 = qp[0], q1 = qp[1];
        float sc[4];
        float mx = -1e30f;
#pragma unroll
        for (int jj = 0; jj < 4; ++jj) {
            const float4* kp = (const float4*)&sqkv[(lo * 4 + jj) * 100 + 32 + h * 8];
            sc[jj] = dot8(q0, q1, kp[0], kp[1]) * scale;
            mx = fmaxf(mx, sc[jj]);
        }
        float den = 0.f;
#pragma unroll
        for (int jj = 0; jj < 4; ++jj) { sc[jj] = __expf(sc[jj] - mx); den += sc[jj]; }
        float inv = 1.f / den;
        float a[8];
#pragma unroll
        for (int dd = 0; dd < 8; ++dd) a[dd] = 0.f;
#pragma unroll
        for (int jj = 0; jj < 4; ++jj) {
            const float4* vp = (const float4*)&sqkv[(lo * 4 + jj) * 100 + 64 + h * 8];
            float4 v0 = vp[0], v1 = vp[1];
            float wgt = sc[jj];
            a[0] += wgt * v0.x;  a[1] += wgt * v0.y;
            a[2] += wgt * v0.z;  a[3] += wgt * v0.w;
            a[4] += wgt * v1.x;  a[5] += wgt * v1.y;
            a[6] += wgt * v1.z;  a[7] += wgt * v1.w;
        }
#pragma unroll
        for (int dd = 0; dd < 8; ++dd) so[lo * 4 + ia][h * 8 + dd] = a[dd] * inv;
    }
    __syncthreads();

    // out proj + residual (2 outputs/thread)
    {
        const int r2 = tid & 15;
        const int cB = tid >> 4;
        float orow[32];
#pragma unroll
        for (int k = 0; k < 32; ++k) orow[k] = so[r2][k];
#pragma unroll
        for (int i = 0; i < 2; ++i) {
            int c = cB + i * 16;
            const float4* wr4 = (const float4*)&w_out[c * 32];
            float acc = b_out[c] + sx[r2][c];
#pragma unroll
            for (int k4 = 0; k4 < 8; ++k4) {
                float4 wv = wr4[k4];
                acc += orow[k4 * 4 + 0] * wv.x + orow[k4 * 4 + 1] * wv.y +
                       orow[k4 * 4 + 2] * wv.z + orow[k4 * 4 + 3] * wv.w;
            }
            sqkv[r2 * 100 + c] = acc;
        }
    }
    __syncthreads();

    // LN normalize per row (pre-gamma) -> so
    {
        const int c = tid & 31;
#pragma unroll
        for (int p = 0; p < 2; ++p) {
            int r = p * 8 + (tid >> 5);
            float v = sqkv[r * 100 + c];
            float s1 = v;
#pragma unroll
            for (int off = 16; off >= 1; off >>= 1) s1 += __shfl_xor(s1, off, 64);
            float mu = s1 * (1.f / 32.f);
            float d = v - mu;
            float s2 = d * d;
#pragma unroll
            for (int off = 16; off >= 1; off >>= 1) s2 += __shfl_xor(s2, off, 64);
            float rstd = rsqrtf(s2 * (1.f / 32.f) + LN_EPS);
            so[r][c] = d * rstd;
        }
    }
    __syncthreads();

    // track mean (gamma/beta folded) + row norm via shuffle: 4 lo x 32 c
    if (tid < 128) {
        const int lo = tid >> 5, c = tid & 31;
        float mval = 0.25f * (so[lo * 4 + 0][c] + so[lo * 4 + 1][c] +
                              so[lo * 4 + 2][c] + so[lo * 4 + 3][c]) * ln_g[c] + ln_b[c];
        m_out[(b * 64 + l0 + lo) * 32 + c] = mval;
        float q2 = mval * mval;
#pragma unroll
        for (int off = 16; off >= 1; off >>= 1) q2 += __shfl_xor(q2, off, 64);
        if (c == 0) nrm_out[b * 64 + l0 + lo] = sqrtf(q2);
    }
}

// ---------------------------------------------------------------------------
// Kernel 3: pair features (measured 19.6 us standalone). 1024 x 256, (256,4).
// ---------------------------------------------------------------------------
__global__ __launch_bounds__(256, 4) void k_pair(
    const float* __restrict__ m, const float* __restrict__ nrm,
    const float* __restrict__ pw, const float* __restrict__ pb,
    const float* __restrict__ pg, const float* __restrict__ pbeta,
    float* __restrict__ out)
{
    __shared__ float smj[64][36];
    __shared__ float sT[4 * 520];
    __shared__ float snj[64];
    __shared__ float sbias[16], sgam[16], sbet[16];

    const int bx = blockIdx.x;
    const int b  = bx >> 4;
    const int i0 = (bx & 15) * 4;
    const int tid = threadIdx.x;
    const int lane = tid & 63, w = tid >> 6;

    const int rem0 = tid, rem1 = tid + 256;
    const float* pw0 = pw + (rem0 >> 5) * 1024 + (rem0 & 31);
    const float* pw1 = pw + (rem1 >> 5) * 1024 + (rem1 & 31);
    float w0[32], w1[32];
#pragma unroll
    for (int c = 0; c < 32; ++c) { w0[c] = pw0[c * 32]; w1[c] = pw1[c * 32]; }

    const float* mb = m + b * 2048;
    for (int n = tid; n < 2048; n += 256) smj[n >> 5][n & 31] = mb[n];
    if (tid < 64) snj[tid] = nrm[b * 64 + tid];
    if (tid < 16) {
        sbias[tid] = pb[tid];
        sgam[tid]  = pg[tid];
        sbet[tid]  = pbeta[tid];
    }
    __syncthreads();

#pragma unroll
    for (int il = 0; il < 4; ++il) {
        const float4* mr4 = (const float4*)&smj[i0 + il][0];
        float a0 = 0.f, a1 = 0.f;
#pragma unroll
        for (int c4 = 0; c4 < 8; ++c4) {
            float4 mv = mr4[c4];
            a0 += mv.x * w0[c4 * 4 + 0] + mv.y * w0[c4 * 4 + 1] +
                  mv.z * w0[c4 * 4 + 2] + mv.w * w0[c4 * 4 + 3];
            a1 += mv.x * w1[c4 * 4 + 0] + mv.y * w1[c4 * 4 + 1] +
                  mv.z * w1[c4 * 4 + 2] + mv.w * w1[c4 * 4 + 3];
        }
        sT[il * 520 + rem0] = a0;
        sT[il * 520 + rem1] = a1;
    }
    __syncthreads();

    const int j = lane;
    float mj[32];
    {
        const float4* mjp = (const float4*)&smj[j][0];
#pragma unroll
        for (int d4 = 0; d4 < 8; ++d4) {
            float4 t = mjp[d4];
            mj[d4 * 4 + 0] = t.x;  mj[d4 * 4 + 1] = t.y;
            mj[d4 * 4 + 2] = t.z;  mj[d4 * 4 + 3] = t.w;
        }
    }
    const float nj = snj[j];

    {
        const int il = w;
        const int ig = i0 + il;
        const float invn = 1.f / fmaxf(snj[ig] * nj, 1e-6f);
        float f[16];
#pragma unroll
        for (int cp = 0; cp < 16; ++cp) {
            const float4* tr = (const float4*)&sT[il * 520 + cp * 32];
            float acc = 0.f;
#pragma unroll
            for (int d4 = 0; d4 < 8; ++d4) {
                float4 tv = tr[d4];
                acc += tv.x * mj[d4 * 4 + 0] + tv.y * mj[d4 * 4 + 1] +
                       tv.z * mj[d4 * 4 + 2] + tv.w * mj[d4 * 4 + 3];
            }
            f[cp] = acc * invn + sbias[cp];
        }
        float mu = 0.f;
#pragma unroll
        for (int cp = 0; cp < 16; ++cp) mu += f[cp];
        mu *= (1.f / 16.f);
        float var = 0.f;
#pragma unroll
        for (int cp = 0; cp < 16; ++cp) { float d = f[cp] - mu; var += d * d; }
        var *= (1.f / 16.f);
        const float rstd = rsqrtf(var + LN_EPS);
#pragma unroll
        for (int cp = 0; cp < 16; ++cp) {
            float v = (f[cp] - mu) * rstd * sgam[cp] + sbet[cp];
            float sl = v / (1.f + __expf(-v));
            out[((b * 16 + cp) * 64 + ig) * 64 + j] = sl;
        }
    }
}

// ---------------------------------------------------------------------------
extern "C" void kernel_launch(void* const* d_in, const int* in_sizes, int n_in,
                              void* d_out, int out_size, void* d_ws, size_t ws_size,
                              hipStream_t stream) {
    const float* ctcf  = (const float*)d_in[0];
    const float* hac   = (const float*)d_in[1];
    const float* me1   = (const float*)d_in[2];
    const float* me3   = (const float*)d_in[3];
    const float* ew    = (const float*)d_in[4];
    const float* ebias = (const float*)d_in[5];
    const float* pe    = (const float*)d_in[6];
    const float* riw   = (const float*)d_in[7];
    const float* rib   = (const float*)d_in[8];
    const float* row_  = (const float*)d_in[9];
    const float* rob   = (const float*)d_in[10];
    const float* rlg   = (const float*)d_in[11];
    const float* rlb   = (const float*)d_in[12];
    const float* ciw   = (const float*)d_in[13];
    const float* cib   = (const float*)d_in[14];
    const float* cow   = (const float*)d_in[15];
    const float* cob   = (const float*)d_in[16];
    const float* clg   = (const float*)d_in[17];
    const float* clb   = (const float*)d_in[18];
    const float* pw    = (const float*)d_in[19];
    const float* pb    = (const float*)d_in[20];
    const float* pg    = (const float*)d_in[21];
    const float* pbt   = (const float*)d_in[22];

    float* outp = (float*)d_out;

    // msaR (2 MB) borrows d_out (16 MB): fully consumed by k_col before
    // k_pair writes out (serial stream). m + norms in ws (~528 KB).
    float* msaR = (float*)d_out;
    float* mbuf = (float*)d_ws;                  // 64*64*32 floats
    float* nbuf = mbuf + 64 * 64 * 32;           // 64*64 floats

    k_row<<<512, 512, 0, stream>>>(ctcf, hac, me1, me3, ew, ebias, pe,
                                   riw, rib, row_, rob, rlg, rlb, msaR);
    k_col<<<1024, 256, 0, stream>>>(msaR, ciw, cib, cow, cob, clg, clb,
                                    mbuf, nbuf);
    k_pair<<<1024, 256, 0, stream>>>(mbuf, nbuf, pw, pb, pg, pbt, outp);
}